// Round 5
// baseline (1052.760 us; speedup 1.0000x reference)
//
#include <hip/hip_runtime.h>
#include <hip/hip_bf16.h>
#include <math.h>

typedef unsigned short u16;
typedef __bf16 bf16x8 __attribute__((ext_vector_type(8)));
typedef float floatx4 __attribute__((ext_vector_type(4)));

#define LORA_SCALING 2.0f   // alpha 32 / rank 16

// Packed fragment-major layout for all GEMM operands:
// matrix [R rows][K cols] -> frag (rt = row/16, kt = k/32), frag index = rt*(K/32)+kt.
// Within a frag (1 KB): lane l (0..63) holds row = rt*16 + (l&15), k = kt*32 + (l>>4)*8 .. +7,
// stored at frag*512 + l*8 (u16 units). One global_load_dwordx4 at base+l*16 = one MFMA operand.

// ---------- helpers ----------
__device__ __forceinline__ u16 f2bf(float f) {
  unsigned u = __float_as_uint(f);
  u += 0x7fffu + ((u >> 16) & 1u);   // round-to-nearest-even
  return (u16)(u >> 16);
}
__device__ __forceinline__ float bflo(unsigned u) { return __uint_as_float(u << 16); }
__device__ __forceinline__ float bfhi(unsigned u) { return __uint_as_float(u & 0xffff0000u); }

// ---------- ws scale-slot zeroing ----------
__global__ void zero_ws_kernel(unsigned* p) {
  if (threadIdx.x < 16) p[threadIdx.x] = 0u;
}

// ---------- per-tensor absmax ----------
__global__ void absmax_kernel(const float* __restrict__ w, long long n4, unsigned* __restrict__ out) {
  long long i = (long long)blockIdx.x * blockDim.x + threadIdx.x;
  long long stride = (long long)gridDim.x * blockDim.x;
  float m = 0.f;
  for (; i < n4; i += stride) {
    float4 v = ((const float4*)w)[i];
    m = fmaxf(m, fmaxf(fmaxf(fabsf(v.x), fabsf(v.y)), fmaxf(fabsf(v.z), fabsf(v.w))));
  }
#pragma unroll
  for (int o = 32; o > 0; o >>= 1) m = fmaxf(m, __shfl_xor(m, o, 64));
  __shared__ float sm[8];
  int lane = threadIdx.x & 63, wv = threadIdx.x >> 6;
  if (lane == 0) sm[wv] = m;
  __syncthreads();
  if (threadIdx.x == 0) {
    float mm = sm[0];
    int nw = blockDim.x >> 6;
    for (int j = 1; j < nw; ++j) mm = fmaxf(mm, sm[j]);
    atomicMax(out, __float_as_uint(mm));
  }
}

// ---------- fake-quant W (fp32 row-major) -> bf16 packed frags ----------
// thread reads contiguous 32B (8 fp32), writes one scattered 16B chunk. kc3 = log2(K/8).
__global__ void quant_pack_kernel(const float* __restrict__ w, const unsigned* __restrict__ amax,
                                  u16* __restrict__ wq, long long nchunk, int kc3) {
  float am = __uint_as_float(*amax);
  float scale = am * (1.0f / 127.0f);
  float inv = 127.0f / am;
  long long c = (long long)blockIdx.x * blockDim.x + threadIdx.x;
  long long stride = (long long)gridDim.x * blockDim.x;
  for (; c < nchunk; c += stride) {
    long long m = c >> kc3;
    int k8 = (int)(c & ((1ll << kc3) - 1));
    int kt = k8 >> 2, q = k8 & 3;
    long long frag = (m >> 4) * ((1ll << kc3) >> 2) + kt;
    long long dst = frag * 64 + ((m & 15) | (q << 4));
    const float4* s = (const float4*)(w + c * 8);
    float4 a = s[0], b = s[1];
    union { u16 h[8]; uint4 v; } o;
    o.h[0] = f2bf(fminf(fmaxf(rintf(a.x * inv), -128.f), 127.f) * scale);
    o.h[1] = f2bf(fminf(fmaxf(rintf(a.y * inv), -128.f), 127.f) * scale);
    o.h[2] = f2bf(fminf(fmaxf(rintf(a.z * inv), -128.f), 127.f) * scale);
    o.h[3] = f2bf(fminf(fmaxf(rintf(a.w * inv), -128.f), 127.f) * scale);
    o.h[4] = f2bf(fminf(fmaxf(rintf(b.x * inv), -128.f), 127.f) * scale);
    o.h[5] = f2bf(fminf(fmaxf(rintf(b.y * inv), -128.f), 127.f) * scale);
    o.h[6] = f2bf(fminf(fmaxf(rintf(b.z * inv), -128.f), 127.f) * scale);
    o.h[7] = f2bf(fminf(fmaxf(rintf(b.w * inv), -128.f), 127.f) * scale);
    ((uint4*)wq)[dst] = o.v;
  }
}

// ---------- fp32 row-major -> bf16 packed frags ----------
__global__ void f2bf_pack_kernel(const float* __restrict__ x, u16* __restrict__ xb,
                                 long long nchunk, int kc3) {
  long long c = (long long)blockIdx.x * blockDim.x + threadIdx.x;
  long long stride = (long long)gridDim.x * blockDim.x;
  for (; c < nchunk; c += stride) {
    long long m = c >> kc3;
    int k8 = (int)(c & ((1ll << kc3) - 1));
    int kt = k8 >> 2, q = k8 & 3;
    long long frag = (m >> 4) * ((1ll << kc3) >> 2) + kt;
    long long dst = frag * 64 + ((m & 15) | (q << 4));
    const float4* s = (const float4*)(x + c * 8);
    float4 a = s[0], b = s[1];
    union { u16 h[8]; uint4 v; } o;
    o.h[0] = f2bf(a.x); o.h[1] = f2bf(a.y); o.h[2] = f2bf(a.z); o.h[3] = f2bf(a.w);
    o.h[4] = f2bf(b.x); o.h[5] = f2bf(b.y); o.h[6] = f2bf(b.z); o.h[7] = f2bf(b.w);
    ((uint4*)xb)[dst] = o.v;
  }
}

// ---------- LoRA t = X(bf16 packed) @ A^T(fp32), rank 16 ----------
__global__ void lora_t_kernel(const u16* __restrict__ X, const float* __restrict__ A,
                              float* __restrict__ T, int K) {
  int r = threadIdx.x & 15;
  int mi = threadIdx.x >> 4;
  long long row = (long long)blockIdx.x * 16 + mi;
  int nk = K >> 5;
  const u16* xp = X + ((row >> 4) * (long long)nk) * 512 + (row & 15) * 8;
  const float* ap = A + (long long)r * K;
  float acc0 = 0.f, acc1 = 0.f;
  for (int k = 0; k < K; k += 16) {
    int k2 = k + 8;
    long long o0 = (long long)(k >> 5) * 512 + ((k >> 3) & 3) * 128;
    long long o1 = (long long)(k2 >> 5) * 512 + ((k2 >> 3) & 3) * 128;
    uint4 x0 = *(const uint4*)(xp + o0);
    uint4 x1 = *(const uint4*)(xp + o1);
    float4 a0 = *(const float4*)(ap + k);
    float4 a1 = *(const float4*)(ap + k + 4);
    float4 a2 = *(const float4*)(ap + k2);
    float4 a3 = *(const float4*)(ap + k2 + 4);
    acc0 += bflo(x0.x) * a0.x + bfhi(x0.x) * a0.y + bflo(x0.y) * a0.z + bfhi(x0.y) * a0.w
          + bflo(x0.z) * a1.x + bfhi(x0.z) * a1.y + bflo(x0.w) * a1.z + bfhi(x0.w) * a1.w;
    acc1 += bflo(x1.x) * a2.x + bfhi(x1.x) * a2.y + bflo(x1.y) * a2.z + bfhi(x1.y) * a2.w
          + bflo(x1.z) * a3.x + bfhi(x1.z) * a3.y + bflo(x1.w) * a3.z + bfhi(x1.w) * a3.w;
  }
  T[row * 16 + r] = acc0 + acc1;
}

// ---------- main GEMM: no LDS, no barriers; direct packed-frag loads + MFMA ----------
// 128x128 block, 256 threads = 4 waves (2x2), each wave 64x64 = 4x4 frags of 16x16x32 bf16.
// Register ping-pong double buffer over kt. Grid: id&7 = XCD, bm-local fastest.
template<int DO_GELU>
__global__ __launch_bounds__(256, 3)
void gemm_qlora_kernel(const u16* __restrict__ Apk, const u16* __restrict__ Bpk,
                       const float* __restrict__ bias, const float* __restrict__ T,
                       const float* __restrict__ Bl, void* __restrict__ outp,
                       int M, int N, int K) {
  const int tid = threadIdx.x;
  const int wave = tid >> 6, lane = tid & 63;
  const int quad = lane >> 4, m16 = lane & 15;

  const int per = (M >> 7) >> 3;          // bm tiles per XCD
  int j = blockIdx.x & 7, t = blockIdx.x >> 3;
  int bm = j * per + (t & (per - 1));
  int bn = t / per;

  const int wm = (wave >> 1) * 64, wn = (wave & 1) * 64;
  const int nk = K >> 5;
  const size_t ms = (size_t)nk * 512;     // frag-row stride (u16)

  const u16* Ab = Apk + (size_t)(bm * 8 + (wm >> 4)) * ms + lane * 8;
  const u16* Bb = Bpk + (size_t)(bn * 8 + (wn >> 4)) * ms + lane * 8;

  floatx4 acc[4][4] = {};
  bf16x8 a0[4], b0[4], a1[4], b1[4];

#pragma unroll
  for (int i = 0; i < 4; ++i) {
    a0[i] = *(const bf16x8*)(Ab + i * ms);
    b0[i] = *(const bf16x8*)(Bb + i * ms);
  }

#pragma unroll 1
  for (int kt = 0; kt < nk; kt += 2) {
    const u16* An = Ab + (size_t)(kt + 1) * 512;
    const u16* Bn = Bb + (size_t)(kt + 1) * 512;
#pragma unroll
    for (int i = 0; i < 4; ++i) {
      a1[i] = *(const bf16x8*)(An + i * ms);
      b1[i] = *(const bf16x8*)(Bn + i * ms);
    }
#pragma unroll
    for (int mt = 0; mt < 4; ++mt)
#pragma unroll
      for (int nt = 0; nt < 4; ++nt)
        acc[mt][nt] = __builtin_amdgcn_mfma_f32_16x16x32_bf16(a0[mt], b0[nt], acc[mt][nt], 0, 0, 0);
    const u16* An2 = Ab + (size_t)(kt + 2) * 512;   // may overrun into pad (unused values)
    const u16* Bn2 = Bb + (size_t)(kt + 2) * 512;
#pragma unroll
    for (int i = 0; i < 4; ++i) {
      a0[i] = *(const bf16x8*)(An2 + i * ms);
      b0[i] = *(const bf16x8*)(Bn2 + i * ms);
    }
#pragma unroll
    for (int mt = 0; mt < 4; ++mt)
#pragma unroll
      for (int nt = 0; nt < 4; ++nt)
        acc[mt][nt] = __builtin_amdgcn_mfma_f32_16x16x32_bf16(a1[mt], b1[nt], acc[mt][nt], 0, 0, 0);
  }

  // epilogue: C/D layout row=(lane>>4)*4+reg, col=lane&15
  const float* Trow = T + (size_t)bm * 128 * 16;
  const float* Blrow = Bl + (size_t)bn * 128 * 16;
#pragma unroll
  for (int mt = 0; mt < 4; ++mt) {
#pragma unroll
    for (int r = 0; r < 4; ++r) {
      int ml = wm + mt * 16 + quad * 4 + r;
      size_t gm = (size_t)bm * 128 + ml;
      const float4* tv = (const float4*)(Trow + (size_t)ml * 16);
      float4 ta = tv[0], tb = tv[1], tc = tv[2], td = tv[3];
#pragma unroll
      for (int nt = 0; nt < 4; ++nt) {
        int nl = wn + nt * 16 + m16;
        size_t gn = (size_t)bn * 128 + nl;
        const float4* bv4 = (const float4*)(Blrow + (size_t)nl * 16);
        float4 ba = bv4[0], bb = bv4[1], bc = bv4[2], bd = bv4[3];
        float lora = ta.x * ba.x + ta.y * ba.y + ta.z * ba.z + ta.w * ba.w
                   + tb.x * bb.x + tb.y * bb.y + tb.z * bb.z + tb.w * bb.w
                   + tc.x * bc.x + tc.y * bc.y + tc.z * bc.z + tc.w * bc.w
                   + td.x * bd.x + td.y * bd.y + td.z * bd.z + td.w * bd.w;
        float v = acc[mt][nt][r] + bias[gn] + LORA_SCALING * lora;
        if (DO_GELU) {
          float g = 0.5f * v * (1.0f + erff(v * 0.70710678118654752f));
          // store into PACKED layout for the next GEMM's A operand ([M][N=F])
          size_t dst = ((gm >> 4) * (size_t)(N >> 5) + (gn >> 5)) * 512
                     + (gm & 15) * 8 + (((gn >> 3) & 3) << 7) + (gn & 7);
          ((u16*)outp)[dst] = f2bf(g);
        } else {
          ((float*)outp)[gm * (size_t)N + gn] = v;
        }
      }
    }
  }
}

// ---------- launch ----------
extern "C" void kernel_launch(void* const* d_in, const int* in_sizes, int n_in,
                              void* d_out, int out_size, void* d_ws, size_t ws_size,
                              hipStream_t stream) {
  const float* x    = (const float*)d_in[0];
  const float* W_fc = (const float*)d_in[1];
  const float* b_fc = (const float*)d_in[2];
  const float* A_fc = (const float*)d_in[3];
  const float* B_fc = (const float*)d_in[4];
  const float* W_pr = (const float*)d_in[5];
  const float* b_pr = (const float*)d_in[6];
  const float* A_pr = (const float*)d_in[7];
  const float* B_pr = (const float*)d_in[8];
  float* out = (float*)d_out;

  const int F = in_sizes[2];                 // 4096
  const int D = in_sizes[6];                 // 1024
  const int M = in_sizes[0] / D;             // 8192
  int dsh = 0; while ((1 << dsh) < D) ++dsh;
  int fsh = 0; while ((1 << fsh) < F) ++fsh;

  const size_t PAD = 1 << 17;                // 128K u16 = 256KB pad per packed buf (prefetch overrun)
  char* ws = (char*)d_ws;
  unsigned* amax = (unsigned*)ws;
  u16* wq_fc = (u16*)(ws + 1024);
  u16* wq_pr = wq_fc + (size_t)F * D + PAD;
  u16* xbf   = wq_pr + (size_t)D * F + PAD;
  u16* gbf   = xbf + (size_t)M * D + PAD;
  float* t1  = (float*)(gbf + (size_t)M * F + PAD);
  float* t2  = t1 + (size_t)M * 16;

  long long wfd4 = (long long)F * D / 4;
  long long wfd8 = (long long)F * D / 8;

  zero_ws_kernel<<<1, 64, 0, stream>>>(amax);
  absmax_kernel<<<1024, 256, 0, stream>>>(W_fc, wfd4, amax + 0);
  absmax_kernel<<<1024, 256, 0, stream>>>(W_pr, wfd4, amax + 1);
  quant_pack_kernel<<<2048, 256, 0, stream>>>(W_fc, amax + 0, wq_fc, wfd8, dsh - 3);
  quant_pack_kernel<<<2048, 256, 0, stream>>>(W_pr, amax + 1, wq_pr, wfd8, fsh - 3);
  f2bf_pack_kernel<<<2048, 256, 0, stream>>>(x, xbf, (long long)M * D / 8, dsh - 3);

  lora_t_kernel<<<M / 16, 256, 0, stream>>>(xbf, A_fc, t1, D);
  gemm_qlora_kernel<1><<<dim3((M / 128) * (F / 128)), 256, 0, stream>>>(
      xbf, wq_fc, b_fc, t1, B_fc, (void*)gbf, M, F, D);
  lora_t_kernel<<<M / 16, 256, 0, stream>>>(gbf, A_pr, t2, F);
  gemm_qlora_kernel<0><<<dim3((M / 128) * (D / 128)), 256, 0, stream>>>(
      gbf, wq_pr, b_pr, t2, B_pr, (void*)out, M, D, F);
}